// Round 14
// baseline (174.646 us; speedup 1.0000x reference)
//
#include <hip/hip_runtime.h>

#define N_NODES 50000
#define N_EDGES 800000
#define NB 196  // ceil(N_NODES / 256)

typedef unsigned int uint;
typedef short bf16x8 __attribute__((ext_vector_type(8)));
typedef float f32x4 __attribute__((ext_vector_type(4)));
typedef uint uint4v __attribute__((ext_vector_type(4)));  // native vec for nontemporal builtins

__device__ __forceinline__ ushort f2bf(float f) {
    union { float f; uint u; } v; v.f = f;
    uint r = (v.u + 0x7FFFu + ((v.u >> 16) & 1u)) >> 16;  // RNE
    return (ushort)r;
}
__device__ __forceinline__ float bf_lo(uint u) { return __uint_as_float(u << 16); }
__device__ __forceinline__ float bf_hi(uint u) { return __uint_as_float(u & 0xFFFF0000u); }

// ---------- fused prep: [0,3125) tobf16(emb) | [3125,3321) zero counts | [3321,3386) W12/bvec ----------
__global__ void k_prep(const float* __restrict__ emb, const float* __restrict__ W1,
                       const float* __restrict__ W2, const float* __restrict__ b1,
                       uint* __restrict__ emb_h, ushort* __restrict__ W12t,
                       float* __restrict__ bvec, int* __restrict__ counts) {
    int b = blockIdx.x;
    int tid = threadIdx.x;
    if (b < 3125) {                       // emb -> bf16 (8 floats/thread)
        int t = b * 256 + tid;
        const float4* i4 = (const float4*)emb + (size_t)t * 2;
        float4 v0 = i4[0], v1 = i4[1];
        uint4 o;
        o.x = (uint)f2bf(v0.x) | ((uint)f2bf(v0.y) << 16);
        o.y = (uint)f2bf(v0.z) | ((uint)f2bf(v0.w) << 16);
        o.z = (uint)f2bf(v1.x) | ((uint)f2bf(v1.y) << 16);
        o.w = (uint)f2bf(v1.z) | ((uint)f2bf(v1.w) << 16);
        ((uint4*)emb_h)[t] = o;
    } else if (b < 3125 + NB) {           // zero counts
        int i = (b - 3125) * 256 + tid;
        if (i < N_NODES) counts[i] = 0;
    } else {                              // W12t[n][k] = bf16(sum_m W1[k][m]W2[m][n]); k=128 -> bvec
        int k = (b - (3125 + NB)) * 2 + (tid >> 7);
        int n = tid & 127;
        float s = 0.f;
        if (k < 128) {
            for (int m = 0; m < 256; ++m) s = fmaf(W1[(size_t)k * 256 + m], W2[(size_t)m * 128 + n], s);
            W12t[(size_t)n * 128 + k] = f2bf(s);
        } else if (k == 128) {
            for (int m = 0; m < 256; ++m) s = fmaf(b1[m], W2[(size_t)m * 128 + n], s);
            bvec[n] = s;
        }
    }
}

// ---------- degree / CSR build ----------

__global__ void k_histrank(const int* __restrict__ dst, int* __restrict__ counts,
                           ushort* __restrict__ rank) {
    int e = blockIdx.x * 256 + threadIdx.x;
    if (e < N_EDGES) rank[e] = (ushort)atomicAdd(&counts[dst[e]], 1);
}

__global__ void k_blocksum(const int* __restrict__ counts, int* __restrict__ bsum) {
    __shared__ int lds[256];
    int t = threadIdx.x;
    int i = blockIdx.x * 256 + t;
    int v = (i < N_NODES) ? counts[i] : 0;
    lds[t] = v;
    __syncthreads();
    for (int off = 128; off > 0; off >>= 1) {
        if (t < off) lds[t] += lds[t + off];
        __syncthreads();
    }
    if (t == 0) bsum[blockIdx.x] = lds[0];
}

__global__ void k_scanb(const int* __restrict__ bsum, int* __restrict__ boff) {
    __shared__ int lds[256];
    int t = threadIdx.x;
    int v = (t < NB) ? bsum[t] : 0;
    lds[t] = v;
    __syncthreads();
    for (int off = 1; off < 256; off <<= 1) {
        int o = (t >= off) ? lds[t - off] : 0;
        __syncthreads();
        lds[t] += o;
        __syncthreads();
    }
    if (t < NB) boff[t] = lds[t] - v;  // exclusive
}

__global__ void k_scatter_rp(const int* __restrict__ counts, const int* __restrict__ boff,
                             int* __restrict__ row_ptr, float* __restrict__ dinv) {
    __shared__ int lds[256];
    int t = threadIdx.x;
    int i = blockIdx.x * 256 + t;
    int v = (i < N_NODES) ? counts[i] : 0;
    lds[t] = v;
    __syncthreads();
    for (int off = 1; off < 256; off <<= 1) {
        int o = (t >= off) ? lds[t - off] : 0;
        __syncthreads();
        lds[t] += o;
        __syncthreads();
    }
    if (i < N_NODES) {
        row_ptr[i] = boff[blockIdx.x] + lds[t] - v;
        dinv[i] = rsqrtf((float)(v + 1));  // +1 self-loop
    }
    if (i == 0) row_ptr[N_NODES] = N_EDGES;
}

// atomic-free CSR fill; entry packs (src<<16) | bf16(dinv[src]).
__global__ void k_fillr(const int* __restrict__ src, const int* __restrict__ dst,
                        const ushort* __restrict__ rank, const int* __restrict__ row_ptr,
                        const float* __restrict__ dinv, uint* __restrict__ csr) {
    int e = blockIdx.x * 256 + threadIdx.x;
    if (e >= N_EDGES) return;
    int s = src[e];
    int pos = row_ptr[dst[e]] + (int)rank[e];
    csr[pos] = ((uint)s << 16) | (uint)f2bf(dinv[s]);
}

// ---------- shared gather core: one wave aggregates one node's 128-feat bf16 row ----------
// 4 quarter-waves x 8-deep unroll = 32 source rows in flight per wave.
// csr reads are non-temporal (streamed once; keep L2 for the table).
__device__ __forceinline__ void gather_core(const uint* __restrict__ xh,
                                            const uint* __restrict__ csr,
                                            int beg, int end, int node, float dd,
                                            int q, int fl, float o[8], float& scn) {
    const uint4* xb = (const uint4*)xh;
    float a[8];
    #pragma unroll
    for (int i = 0; i < 8; ++i) a[i] = 0.f;
    float sc = 0.f;

    for (int j = beg + q; j < end; j += 32) {
        uint e0 = __builtin_nontemporal_load(&csr[j]);
        uint def = e0 & 0xFFFF0000u;   // c=0, valid src
        uint e[8];
        e[0] = e0;
        #pragma unroll
        for (int i = 1; i < 8; ++i) {
            int ji = j + 4 * i;
            e[i] = (ji < end) ? __builtin_nontemporal_load(&csr[ji]) : def;
        }
        uint4 u[8];
        #pragma unroll
        for (int i = 0; i < 8; ++i) u[i] = xb[(size_t)(e[i] >> 16) * 16 + fl];
        #pragma unroll
        for (int i = 0; i < 8; ++i) {
            float c = bf_lo(e[i]);
            sc += c;
            a[0] = fmaf(c, bf_lo(u[i].x), a[0]); a[1] = fmaf(c, bf_hi(u[i].x), a[1]);
            a[2] = fmaf(c, bf_lo(u[i].y), a[2]); a[3] = fmaf(c, bf_hi(u[i].y), a[3]);
            a[4] = fmaf(c, bf_lo(u[i].z), a[4]); a[5] = fmaf(c, bf_hi(u[i].z), a[5]);
            a[6] = fmaf(c, bf_lo(u[i].w), a[6]); a[7] = fmaf(c, bf_hi(u[i].w), a[7]);
        }
    }
    #pragma unroll
    for (int off = 16; off < 64; off <<= 1) {
        #pragma unroll
        for (int i = 0; i < 8; ++i) a[i] += __shfl_xor(a[i], off);
        sc += __shfl_xor(sc, off);
    }
    float dd2 = dd * dd;
    const uint4* xs = (const uint4*)xh + (size_t)node * 16 + fl;
    uint4 u = *xs;
    float s[8] = { bf_lo(u.x), bf_hi(u.x), bf_lo(u.y), bf_hi(u.y),
                   bf_lo(u.z), bf_hi(u.z), bf_lo(u.w), bf_hi(u.w) };
    #pragma unroll
    for (int i = 0; i < 8; ++i) o[i] = fmaf(dd, a[i], dd2 * s[i]);
    scn = fmaf(dd, sc, dd2);
}

// ---------- gather1: G = bf16(Agg(emb)), nontemporal output ----------
__global__ void k_gather1(const uint* __restrict__ xh, const uint* __restrict__ csr,
                          const int* __restrict__ rp, const float* __restrict__ dinv,
                          uint* __restrict__ outp) {
    int node = blockIdx.x * 4 + (threadIdx.x >> 6);
    int lane = threadIdx.x & 63;
    int q = lane >> 4, fl = lane & 15;
    int beg = rp[node], end = rp[node + 1];
    float o[8], scn;
    gather_core(xh, csr, beg, end, node, dinv[node], q, fl, o, scn);
    if (q == 0) {
        uint4v p;
        p.x = (uint)f2bf(o[0]) | ((uint)f2bf(o[1]) << 16);
        p.y = (uint)f2bf(o[2]) | ((uint)f2bf(o[3]) << 16);
        p.z = (uint)f2bf(o[4]) | ((uint)f2bf(o[5]) << 16);
        p.w = (uint)f2bf(o[6]) | ((uint)f2bf(o[7]) << 16);
        __builtin_nontemporal_store(p, (uint4v*)outp + (size_t)node * 16 + fl);
    }
}

// ---------- gather2: G2 = bf16(Agg(G)), plus nvec ----------
__global__ void k_gather2(const uint* __restrict__ xh, const uint* __restrict__ csr,
                          const int* __restrict__ rp, const float* __restrict__ dinv,
                          uint* __restrict__ outp, float* __restrict__ nvec) {
    int node = blockIdx.x * 4 + (threadIdx.x >> 6);
    int lane = threadIdx.x & 63;
    int q = lane >> 4, fl = lane & 15;
    int beg = rp[node], end = rp[node + 1];
    float o[8], scn;
    gather_core(xh, csr, beg, end, node, dinv[node], q, fl, o, scn);
    if (q == 0) {
        uint4v p;
        p.x = (uint)f2bf(o[0]) | ((uint)f2bf(o[1]) << 16);
        p.y = (uint)f2bf(o[2]) | ((uint)f2bf(o[3]) << 16);
        p.z = (uint)f2bf(o[4]) | ((uint)f2bf(o[5]) << 16);
        p.w = (uint)f2bf(o[6]) | ((uint)f2bf(o[7]) << 16);
        __builtin_nontemporal_store(p, (uint4v*)outp + (size_t)node * 16 + fl);
        if (fl == 0) nvec[node] = scn;
    }
}

// ---------- final MFMA GEMM: out[16r][128] fp32 = G2[16r][128]bf16 @ W12t[128][128]
//            + nvec[r]*bvec[c] + b2[c] ----------
__global__ void __launch_bounds__(256)
k_gemm_out(const ushort* __restrict__ A, const ushort* __restrict__ Wt,
           const float* __restrict__ nvec, const float* __restrict__ bvec,
           const float* __restrict__ b2, float* __restrict__ out) {
    constexpr int K = 128, NC = 128, KC = 4, TPW = 2;
    const int lane = threadIdx.x & 63;
    const int wave = threadIdx.x >> 6;
    const int row0 = blockIdx.x * 16;
    const int r = row0 + (lane & 15);
    const int ksub = (lane >> 4) * 8;

    f32x4 acc[TPW];
    int col[TPW];
    #pragma unroll
    for (int t = 0; t < TPW; ++t) {
        acc[t] = (f32x4){0.f, 0.f, 0.f, 0.f};
        col[t] = (wave * TPW + t) * 16 + (lane & 15);
    }
    #pragma unroll
    for (int kc = 0; kc < KC; ++kc) {
        bf16x8 af = *(const bf16x8*)(A + (size_t)r * K + kc * 32 + ksub);
        #pragma unroll
        for (int t = 0; t < TPW; ++t) {
            bf16x8 bf = *(const bf16x8*)(Wt + (size_t)col[t] * K + kc * 32 + ksub);
            acc[t] = __builtin_amdgcn_mfma_f32_16x16x32_bf16(af, bf, acc[t], 0, 0, 0);
        }
    }
    const int rb = row0 + (lane >> 4) * 4;
    float nv[4];
    #pragma unroll
    for (int e = 0; e < 4; ++e) nv[e] = nvec[rb + e];
    #pragma unroll
    for (int t = 0; t < TPW; ++t) {
        float bv = bvec[col[t]];
        float bb = b2[col[t]];
        #pragma unroll
        for (int e = 0; e < 4; ++e) {
            out[(size_t)(rb + e) * NC + col[t]] = acc[t][e] + nv[e] * bv + bb;
        }
    }
}

extern "C" void kernel_launch(void* const* d_in, const int* in_sizes, int n_in,
                              void* d_out, int out_size, void* d_ws, size_t ws_size,
                              hipStream_t stream) {
    const float* emb = (const float*)d_in[0];   // [50000][128]
    const float* W1  = (const float*)d_in[1];   // [128][256]
    const float* b1  = (const float*)d_in[2];   // [256]
    const float* W2  = (const float*)d_in[3];   // [256][128]
    const float* b2  = (const float*)d_in[4];   // [128]
    const int*   ei  = (const int*)d_in[5];     // [2][800000]
    const int* src = ei;
    const int* dst = ei + N_EDGES;

    char* ws = (char*)d_ws;
    float*  dinv    = (float*) (ws);                    // 200 KB
    int*    counts  = (int*)   (ws + (256ull << 10));   // 200 KB
    int*    row_ptr = (int*)   (ws + (512ull << 10));   // 200 KB + 4
    int*    bsum    = (int*)   (ws + (768ull << 10));   // 784 B
    int*    boff    = (int*)   (ws + (772ull << 10));   // 784 B
    ushort* rank    = (ushort*)(ws + (1ull << 20));     // 1.6 MB  (1..2.6)
    uint*   csr     = (uint*)  (ws + (3ull << 20));     // 3.2 MB  (3..6.2)
    ushort* W12t    = (ushort*)(ws + (6656ull << 10));  // 32 KB   (6.5MB)
    float*  bvec    = (float*) (ws + (6720ull << 10));  // 512 B
    float*  nvec    = (float*) (ws + (6784ull << 10));  // 200 KB
    uint*   emb_h   = (uint*)  (ws + (7ull  << 20));    // 12.8 MB (7..19.8)
    uint*   G       = (uint*)  (ws + (20ull << 20));    // 12.8 MB (20..32.8)
    uint*   G2      = (uint*)  (ws + (33ull << 20));    // 12.8 MB (33..45.8)
    float*  out     = (float*)d_out;

    // fused prep: emb->bf16, zero counts, W12t/bvec
    k_prep<<<3386, 256, 0, stream>>>(emb, W1, W2, b1, emb_h, W12t, bvec, counts);

    // CSR build + normalization
    k_histrank<<<(N_EDGES + 255) / 256, 256, 0, stream>>>(dst, counts, rank);
    k_blocksum<<<NB, 256, 0, stream>>>(counts, bsum);
    k_scanb<<<1, 256, 0, stream>>>(bsum, boff);
    k_scatter_rp<<<NB, 256, 0, stream>>>(counts, boff, row_ptr, dinv);
    k_fillr<<<(N_EDGES + 255) / 256, 256, 0, stream>>>(src, dst, rank, row_ptr, dinv, csr);

    // out = (N^2 emb) @ (W1W2) + (N·1)(b1W2) + b2
    k_gather1<<<12500, 256, 0, stream>>>(emb_h, csr, row_ptr, dinv, G);
    k_gather2<<<12500, 256, 0, stream>>>(G, csr, row_ptr, dinv, G2, nvec);
    k_gemm_out<<<N_NODES / 16, 256, 0, stream>>>((const ushort*)G2, W12t, nvec, bvec, b2, out);
}

// Round 15
// 155.409 us; speedup vs baseline: 1.1238x; 1.1238x over previous
//
#include <hip/hip_runtime.h>

#define N_NODES 50000
#define N_EDGES 800000
#define NB 196  // ceil(N_NODES / 256)

typedef unsigned int uint;
typedef short bf16x8 __attribute__((ext_vector_type(8)));
typedef float f32x4 __attribute__((ext_vector_type(4)));

__device__ __forceinline__ ushort f2bf(float f) {
    union { float f; uint u; } v; v.f = f;
    uint r = (v.u + 0x7FFFu + ((v.u >> 16) & 1u)) >> 16;  // RNE
    return (ushort)r;
}
__device__ __forceinline__ float bf_lo(uint u) { return __uint_as_float(u << 16); }
__device__ __forceinline__ float bf_hi(uint u) { return __uint_as_float(u & 0xFFFF0000u); }

// ---------- fused prep: [0,3125) tobf16(emb) | [3125,3321) zero counts | [3321,3386) W12/bvec ----------
__global__ void k_prep(const float* __restrict__ emb, const float* __restrict__ W1,
                       const float* __restrict__ W2, const float* __restrict__ b1,
                       uint* __restrict__ emb_h, ushort* __restrict__ W12t,
                       float* __restrict__ bvec, int* __restrict__ counts) {
    int b = blockIdx.x;
    int tid = threadIdx.x;
    if (b < 3125) {                       // emb -> bf16 (8 floats/thread)
        int t = b * 256 + tid;
        const float4* i4 = (const float4*)emb + (size_t)t * 2;
        float4 v0 = i4[0], v1 = i4[1];
        uint4 o;
        o.x = (uint)f2bf(v0.x) | ((uint)f2bf(v0.y) << 16);
        o.y = (uint)f2bf(v0.z) | ((uint)f2bf(v0.w) << 16);
        o.z = (uint)f2bf(v1.x) | ((uint)f2bf(v1.y) << 16);
        o.w = (uint)f2bf(v1.z) | ((uint)f2bf(v1.w) << 16);
        ((uint4*)emb_h)[t] = o;
    } else if (b < 3125 + NB) {           // zero counts
        int i = (b - 3125) * 256 + tid;
        if (i < N_NODES) counts[i] = 0;
    } else {                              // W12t[n][k] = bf16(sum_m W1[k][m]W2[m][n]); k=128 -> bvec
        int k = (b - (3125 + NB)) * 2 + (tid >> 7);
        int n = tid & 127;
        float s = 0.f;
        if (k < 128) {
            for (int m = 0; m < 256; ++m) s = fmaf(W1[(size_t)k * 256 + m], W2[(size_t)m * 128 + n], s);
            W12t[(size_t)n * 128 + k] = f2bf(s);
        } else if (k == 128) {
            for (int m = 0; m < 256; ++m) s = fmaf(b1[m], W2[(size_t)m * 128 + n], s);
            bvec[n] = s;
        }
    }
}

// ---------- degree / CSR build ----------

__global__ void k_histrank(const int* __restrict__ dst, int* __restrict__ counts,
                           ushort* __restrict__ rank) {
    int e = blockIdx.x * 256 + threadIdx.x;
    if (e < N_EDGES) rank[e] = (ushort)atomicAdd(&counts[dst[e]], 1);
}

__global__ void k_blocksum(const int* __restrict__ counts, int* __restrict__ bsum) {
    __shared__ int lds[256];
    int t = threadIdx.x;
    int i = blockIdx.x * 256 + t;
    int v = (i < N_NODES) ? counts[i] : 0;
    lds[t] = v;
    __syncthreads();
    for (int off = 128; off > 0; off >>= 1) {
        if (t < off) lds[t] += lds[t + off];
        __syncthreads();
    }
    if (t == 0) bsum[blockIdx.x] = lds[0];
}

// row_ptr/dinv; block base computed inline from bsum (masked reduce, no scanb kernel).
__global__ void k_scatter_rp(const int* __restrict__ counts, const int* __restrict__ bsum,
                             int* __restrict__ row_ptr, float* __restrict__ dinv) {
    __shared__ int lds[256];
    int t = threadIdx.x;
    // base = sum_{j < blockIdx.x} bsum[j]   (blockIdx.x <= 195 < 256)
    lds[t] = (t < blockIdx.x) ? bsum[t] : 0;
    __syncthreads();
    for (int off = 128; off > 0; off >>= 1) {
        if (t < off) lds[t] += lds[t + off];
        __syncthreads();
    }
    int base = lds[0];
    __syncthreads();
    // in-block exclusive scan of counts
    int i = blockIdx.x * 256 + t;
    int v = (i < N_NODES) ? counts[i] : 0;
    lds[t] = v;
    __syncthreads();
    for (int off = 1; off < 256; off <<= 1) {
        int o = (t >= off) ? lds[t - off] : 0;
        __syncthreads();
        lds[t] += o;
        __syncthreads();
    }
    if (i < N_NODES) {
        row_ptr[i] = base + lds[t] - v;
        dinv[i] = rsqrtf((float)(v + 1));  // +1 self-loop
    }
    if (i == 0) row_ptr[N_NODES] = N_EDGES;
}

// atomic-free CSR fill; entry packs (src<<16) | bf16(dinv[src]).
__global__ void k_fillr(const int* __restrict__ src, const int* __restrict__ dst,
                        const ushort* __restrict__ rank, const int* __restrict__ row_ptr,
                        const float* __restrict__ dinv, uint* __restrict__ csr) {
    int e = blockIdx.x * 256 + threadIdx.x;
    if (e >= N_EDGES) return;
    int s = src[e];
    int pos = row_ptr[dst[e]] + (int)rank[e];
    csr[pos] = ((uint)s << 16) | (uint)f2bf(dinv[s]);
}

// ---------- gather aggregation over bf16 table (F=128, one wave per dst) ----------
// CSR entry = (src<<16)|bf16(dinv[src]) -> no per-edge dinv load.
// 4 quarter-waves x 4-deep unroll = 16 rows in flight per wave (matches avg degree).
// NVEC: also write nvec[d] = dinv[d]*sum_s dinv[s] + dinv[d]^2.
template<bool NVEC>
__global__ void k_gather128h(const uint* __restrict__ xh, const uint* __restrict__ csr,
                             const int* __restrict__ rp, const float* __restrict__ dinv,
                             uint* __restrict__ outp, float* __restrict__ nvec) {
    int node = blockIdx.x * 4 + (threadIdx.x >> 6);
    int lane = threadIdx.x & 63;
    int q = lane >> 4;
    int fl = lane & 15;
    int beg = rp[node], end = rp[node + 1];
    const uint4* xb = (const uint4*)xh;  // row s = 16 uint4s
    float a[8];
    #pragma unroll
    for (int i = 0; i < 8; ++i) a[i] = 0.f;
    float sc = 0.f;

    for (int j = beg + q; j < end; j += 16) {
        int j1 = j + 4, j2 = j + 8, j3 = j + 12;
        uint e0 = csr[j];
        uint e1 = (j1 < end) ? csr[j1] : (e0 & 0xFFFF0000u);
        uint e2 = (j2 < end) ? csr[j2] : (e0 & 0xFFFF0000u);
        uint e3 = (j3 < end) ? csr[j3] : (e0 & 0xFFFF0000u);
        int s0 = e0 >> 16, s1 = e1 >> 16, s2 = e2 >> 16, s3 = e3 >> 16;
        float c0 = bf_lo(e0), c1 = bf_lo(e1), c2 = bf_lo(e2), c3 = bf_lo(e3);
        uint4 u0 = xb[(size_t)s0 * 16 + fl];
        uint4 u1 = xb[(size_t)s1 * 16 + fl];
        uint4 u2 = xb[(size_t)s2 * 16 + fl];
        uint4 u3 = xb[(size_t)s3 * 16 + fl];
        sc += c0 + c1 + c2 + c3;
        a[0] = fmaf(c0, bf_lo(u0.x), a[0]); a[1] = fmaf(c0, bf_hi(u0.x), a[1]);
        a[2] = fmaf(c0, bf_lo(u0.y), a[2]); a[3] = fmaf(c0, bf_hi(u0.y), a[3]);
        a[4] = fmaf(c0, bf_lo(u0.z), a[4]); a[5] = fmaf(c0, bf_hi(u0.z), a[5]);
        a[6] = fmaf(c0, bf_lo(u0.w), a[6]); a[7] = fmaf(c0, bf_hi(u0.w), a[7]);
        a[0] = fmaf(c1, bf_lo(u1.x), a[0]); a[1] = fmaf(c1, bf_hi(u1.x), a[1]);
        a[2] = fmaf(c1, bf_lo(u1.y), a[2]); a[3] = fmaf(c1, bf_hi(u1.y), a[3]);
        a[4] = fmaf(c1, bf_lo(u1.z), a[4]); a[5] = fmaf(c1, bf_hi(u1.z), a[5]);
        a[6] = fmaf(c1, bf_lo(u1.w), a[6]); a[7] = fmaf(c1, bf_hi(u1.w), a[7]);
        a[0] = fmaf(c2, bf_lo(u2.x), a[0]); a[1] = fmaf(c2, bf_hi(u2.x), a[1]);
        a[2] = fmaf(c2, bf_lo(u2.y), a[2]); a[3] = fmaf(c2, bf_hi(u2.y), a[3]);
        a[4] = fmaf(c2, bf_lo(u2.z), a[4]); a[5] = fmaf(c2, bf_hi(u2.z), a[5]);
        a[6] = fmaf(c2, bf_lo(u2.w), a[6]); a[7] = fmaf(c2, bf_hi(u2.w), a[7]);
        a[0] = fmaf(c3, bf_lo(u3.x), a[0]); a[1] = fmaf(c3, bf_hi(u3.x), a[1]);
        a[2] = fmaf(c3, bf_lo(u3.y), a[2]); a[3] = fmaf(c3, bf_hi(u3.y), a[3]);
        a[4] = fmaf(c3, bf_lo(u3.z), a[4]); a[5] = fmaf(c3, bf_hi(u3.z), a[5]);
        a[6] = fmaf(c3, bf_lo(u3.w), a[6]); a[7] = fmaf(c3, bf_hi(u3.w), a[7]);
    }
    #pragma unroll
    for (int off = 16; off < 64; off <<= 1) {
        #pragma unroll
        for (int i = 0; i < 8; ++i) a[i] += __shfl_xor(a[i], off);
        if (NVEC) sc += __shfl_xor(sc, off);
    }
    if (q == 0) {
        float dd = dinv[node];
        float dd2 = dd * dd;
        uint4 u = xb[(size_t)node * 16 + fl];
        float s[8] = { bf_lo(u.x), bf_hi(u.x), bf_lo(u.y), bf_hi(u.y),
                       bf_lo(u.z), bf_hi(u.z), bf_lo(u.w), bf_hi(u.w) };
        uint4 p;
        float o0 = fmaf(dd, a[0], dd2 * s[0]), o1 = fmaf(dd, a[1], dd2 * s[1]);
        float o2 = fmaf(dd, a[2], dd2 * s[2]), o3 = fmaf(dd, a[3], dd2 * s[3]);
        float o4 = fmaf(dd, a[4], dd2 * s[4]), o5 = fmaf(dd, a[5], dd2 * s[5]);
        float o6 = fmaf(dd, a[6], dd2 * s[6]), o7 = fmaf(dd, a[7], dd2 * s[7]);
        p.x = (uint)f2bf(o0) | ((uint)f2bf(o1) << 16);
        p.y = (uint)f2bf(o2) | ((uint)f2bf(o3) << 16);
        p.z = (uint)f2bf(o4) | ((uint)f2bf(o5) << 16);
        p.w = (uint)f2bf(o6) | ((uint)f2bf(o7) << 16);
        ((uint4*)outp)[(size_t)node * 16 + fl] = p;
        if (NVEC && fl == 0) nvec[node] = fmaf(dd, sc, dd2);
    }
}

// ---------- final MFMA GEMM: out[16r][128] fp32 = G2[16r][128]bf16 @ W12t[128][128]
//            + nvec[r]*bvec[c] + b2[c] ----------
__global__ void __launch_bounds__(256)
k_gemm_out(const ushort* __restrict__ A, const ushort* __restrict__ Wt,
           const float* __restrict__ nvec, const float* __restrict__ bvec,
           const float* __restrict__ b2, float* __restrict__ out) {
    constexpr int K = 128, NC = 128, KC = 4, TPW = 2;
    const int lane = threadIdx.x & 63;
    const int wave = threadIdx.x >> 6;
    const int row0 = blockIdx.x * 16;
    const int r = row0 + (lane & 15);
    const int ksub = (lane >> 4) * 8;

    f32x4 acc[TPW];
    int col[TPW];
    #pragma unroll
    for (int t = 0; t < TPW; ++t) {
        acc[t] = (f32x4){0.f, 0.f, 0.f, 0.f};
        col[t] = (wave * TPW + t) * 16 + (lane & 15);
    }
    #pragma unroll
    for (int kc = 0; kc < KC; ++kc) {
        bf16x8 af = *(const bf16x8*)(A + (size_t)r * K + kc * 32 + ksub);
        #pragma unroll
        for (int t = 0; t < TPW; ++t) {
            bf16x8 bf = *(const bf16x8*)(Wt + (size_t)col[t] * K + kc * 32 + ksub);
            acc[t] = __builtin_amdgcn_mfma_f32_16x16x32_bf16(af, bf, acc[t], 0, 0, 0);
        }
    }
    const int rb = row0 + (lane >> 4) * 4;
    float nv[4];
    #pragma unroll
    for (int e = 0; e < 4; ++e) nv[e] = nvec[rb + e];
    #pragma unroll
    for (int t = 0; t < TPW; ++t) {
        float bv = bvec[col[t]];
        float bb = b2[col[t]];
        #pragma unroll
        for (int e = 0; e < 4; ++e) {
            out[(size_t)(rb + e) * NC + col[t]] = acc[t][e] + nv[e] * bv + bb;
        }
    }
}

extern "C" void kernel_launch(void* const* d_in, const int* in_sizes, int n_in,
                              void* d_out, int out_size, void* d_ws, size_t ws_size,
                              hipStream_t stream) {
    const float* emb = (const float*)d_in[0];   // [50000][128]
    const float* W1  = (const float*)d_in[1];   // [128][256]
    const float* b1  = (const float*)d_in[2];   // [256]
    const float* W2  = (const float*)d_in[3];   // [256][128]
    const float* b2  = (const float*)d_in[4];   // [128]
    const int*   ei  = (const int*)d_in[5];     // [2][800000]
    const int* src = ei;
    const int* dst = ei + N_EDGES;

    char* ws = (char*)d_ws;
    float*  dinv    = (float*) (ws);                    // 200 KB
    int*    counts  = (int*)   (ws + (256ull << 10));   // 200 KB
    int*    row_ptr = (int*)   (ws + (512ull << 10));   // 200 KB + 4
    int*    bsum    = (int*)   (ws + (768ull << 10));   // 784 B
    ushort* rank    = (ushort*)(ws + (1ull << 20));     // 1.6 MB  (1..2.6)
    uint*   csr     = (uint*)  (ws + (3ull << 20));     // 3.2 MB  (3..6.2)
    ushort* W12t    = (ushort*)(ws + (6656ull << 10));  // 32 KB   (6.5MB)
    float*  bvec    = (float*) (ws + (6720ull << 10));  // 512 B
    float*  nvec    = (float*) (ws + (6784ull << 10));  // 200 KB
    uint*   emb_h   = (uint*)  (ws + (7ull  << 20));    // 12.8 MB (7..19.8)
    uint*   G       = (uint*)  (ws + (20ull << 20));    // 12.8 MB (20..32.8)
    uint*   G2      = (uint*)  (ws + (33ull << 20));    // 12.8 MB (33..45.8)
    float*  out     = (float*)d_out;

    // fused prep: emb->bf16, zero counts, W12t/bvec
    k_prep<<<3386, 256, 0, stream>>>(emb, W1, W2, b1, emb_h, W12t, bvec, counts);

    // CSR build + normalization (scanb folded into scatter_rp)
    k_histrank<<<(N_EDGES + 255) / 256, 256, 0, stream>>>(dst, counts, rank);
    k_blocksum<<<NB, 256, 0, stream>>>(counts, bsum);
    k_scatter_rp<<<NB, 256, 0, stream>>>(counts, bsum, row_ptr, dinv);
    k_fillr<<<(N_EDGES + 255) / 256, 256, 0, stream>>>(src, dst, rank, row_ptr, dinv, csr);

    // out = (N^2 emb) @ (W1W2) + (N·1)(b1W2) + b2
    k_gather128h<false><<<12500, 256, 0, stream>>>(emb_h, csr, row_ptr, dinv, G, nullptr);
    k_gather128h<true><<<12500, 256, 0, stream>>>(G, csr, row_ptr, dinv, G2, nvec);
    k_gemm_out<<<N_NODES / 16, 256, 0, stream>>>((const ushort*)G2, W12t, nvec, bvec, b2, out);
}

// Round 16
// 154.383 us; speedup vs baseline: 1.1313x; 1.0066x over previous
//
#include <hip/hip_runtime.h>

#define N_NODES 50000
#define N_EDGES 800000
#define NB 196  // ceil(N_NODES / 256)

typedef unsigned int uint;
typedef short bf16x8 __attribute__((ext_vector_type(8)));
typedef float f32x4 __attribute__((ext_vector_type(4)));

__device__ __forceinline__ ushort f2bf(float f) {
    union { float f; uint u; } v; v.f = f;
    uint r = (v.u + 0x7FFFu + ((v.u >> 16) & 1u)) >> 16;  // RNE
    return (ushort)r;
}
__device__ __forceinline__ float bf_lo(uint u) { return __uint_as_float(u << 16); }
__device__ __forceinline__ float bf_hi(uint u) { return __uint_as_float(u & 0xFFFF0000u); }

// ---------- fused prep: [0,3125) tobf16(emb) | [3125,3321) zero counts | [3321,3386) W12/bvec ----------
__global__ void k_prep(const float* __restrict__ emb, const float* __restrict__ W1,
                       const float* __restrict__ W2, const float* __restrict__ b1,
                       uint* __restrict__ emb_h, ushort* __restrict__ W12t,
                       float* __restrict__ bvec, int* __restrict__ counts) {
    int b = blockIdx.x;
    int tid = threadIdx.x;
    if (b < 3125) {                       // emb -> bf16 (8 floats/thread)
        int t = b * 256 + tid;
        const float4* i4 = (const float4*)emb + (size_t)t * 2;
        float4 v0 = i4[0], v1 = i4[1];
        uint4 o;
        o.x = (uint)f2bf(v0.x) | ((uint)f2bf(v0.y) << 16);
        o.y = (uint)f2bf(v0.z) | ((uint)f2bf(v0.w) << 16);
        o.z = (uint)f2bf(v1.x) | ((uint)f2bf(v1.y) << 16);
        o.w = (uint)f2bf(v1.z) | ((uint)f2bf(v1.w) << 16);
        ((uint4*)emb_h)[t] = o;
    } else if (b < 3125 + NB) {           // zero counts
        int i = (b - 3125) * 256 + tid;
        if (i < N_NODES) counts[i] = 0;
    } else {                              // W12t[n][k] = bf16(sum_m W1[k][m]W2[m][n]); k=128 -> bvec
        int k = (b - (3125 + NB)) * 2 + (tid >> 7);
        int n = tid & 127;
        float s = 0.f;
        if (k < 128) {
            for (int m = 0; m < 256; ++m) s = fmaf(W1[(size_t)k * 256 + m], W2[(size_t)m * 128 + n], s);
            W12t[(size_t)n * 128 + k] = f2bf(s);
        } else if (k == 128) {
            for (int m = 0; m < 256; ++m) s = fmaf(b1[m], W2[(size_t)m * 128 + n], s);
            bvec[n] = s;
        }
    }
}

// ---------- degree / CSR build ----------

__global__ void k_histrank(const int* __restrict__ dst, int* __restrict__ counts,
                           ushort* __restrict__ rank) {
    int e = blockIdx.x * 256 + threadIdx.x;
    if (e < N_EDGES) rank[e] = (ushort)atomicAdd(&counts[dst[e]], 1);
}

__global__ void k_blocksum(const int* __restrict__ counts, int* __restrict__ bsum) {
    __shared__ int lds[256];
    int t = threadIdx.x;
    int i = blockIdx.x * 256 + t;
    int v = (i < N_NODES) ? counts[i] : 0;
    lds[t] = v;
    __syncthreads();
    for (int off = 128; off > 0; off >>= 1) {
        if (t < off) lds[t] += lds[t + off];
        __syncthreads();
    }
    if (t == 0) bsum[blockIdx.x] = lds[0];
}

// row_ptr/dinv; block base computed inline from bsum (masked reduce, no scanb kernel).
__global__ void k_scatter_rp(const int* __restrict__ counts, const int* __restrict__ bsum,
                             int* __restrict__ row_ptr, float* __restrict__ dinv) {
    __shared__ int lds[256];
    int t = threadIdx.x;
    lds[t] = (t < blockIdx.x) ? bsum[t] : 0;
    __syncthreads();
    for (int off = 128; off > 0; off >>= 1) {
        if (t < off) lds[t] += lds[t + off];
        __syncthreads();
    }
    int base = lds[0];
    __syncthreads();
    int i = blockIdx.x * 256 + t;
    int v = (i < N_NODES) ? counts[i] : 0;
    lds[t] = v;
    __syncthreads();
    for (int off = 1; off < 256; off <<= 1) {
        int o = (t >= off) ? lds[t - off] : 0;
        __syncthreads();
        lds[t] += o;
        __syncthreads();
    }
    if (i < N_NODES) {
        row_ptr[i] = base + lds[t] - v;
        dinv[i] = rsqrtf((float)(v + 1));  // +1 self-loop
    }
    if (i == 0) row_ptr[N_NODES] = N_EDGES;
}

// atomic-free CSR fill; entry packs (src<<16) | bf16(dinv[src]).
__global__ void k_fillr(const int* __restrict__ src, const int* __restrict__ dst,
                        const ushort* __restrict__ rank, const int* __restrict__ row_ptr,
                        const float* __restrict__ dinv, uint* __restrict__ csr) {
    int e = blockIdx.x * 256 + threadIdx.x;
    if (e >= N_EDGES) return;
    int s = src[e];
    int pos = row_ptr[dst[e]] + (int)rank[e];
    csr[pos] = ((uint)s << 16) | (uint)f2bf(dinv[s]);
}

// ---------- gather: one 16-lane quarter-wave per node (no cross-quarter reduce) ----------
// Block 256 = 16 quarters = 16 nodes; grid 3125. Lane fl covers feats [fl*8, fl*8+8).
// CSR entry = (src<<16)|bf16(dinv[src]). 4-deep unroll per iteration.
// NVEC: sc is replicated across the quarter; lane fl==0 writes nvec.
template<bool NVEC>
__global__ void k_gatherq(const uint* __restrict__ xh, const uint* __restrict__ csr,
                          const int* __restrict__ rp, const float* __restrict__ dinv,
                          uint* __restrict__ outp, float* __restrict__ nvec) {
    int node = blockIdx.x * 16 + (threadIdx.x >> 4);
    int fl = threadIdx.x & 15;
    int beg = rp[node], end = rp[node + 1];
    const uint4* xb = (const uint4*)xh;  // row s = 16 uint4s
    float a[8];
    #pragma unroll
    for (int i = 0; i < 8; ++i) a[i] = 0.f;
    float sc = 0.f;

    for (int j = beg; j < end; j += 4) {
        uint e0 = csr[j];
        uint def = e0 & 0xFFFF0000u;   // c=0, valid src
        uint e1 = (j + 1 < end) ? csr[j + 1] : def;
        uint e2 = (j + 2 < end) ? csr[j + 2] : def;
        uint e3 = (j + 3 < end) ? csr[j + 3] : def;
        int s0 = e0 >> 16, s1 = e1 >> 16, s2 = e2 >> 16, s3 = e3 >> 16;
        float c0 = bf_lo(e0), c1 = bf_lo(e1), c2 = bf_lo(e2), c3 = bf_lo(e3);
        uint4 u0 = xb[(size_t)s0 * 16 + fl];
        uint4 u1 = xb[(size_t)s1 * 16 + fl];
        uint4 u2 = xb[(size_t)s2 * 16 + fl];
        uint4 u3 = xb[(size_t)s3 * 16 + fl];
        sc += c0 + c1 + c2 + c3;
        a[0] = fmaf(c0, bf_lo(u0.x), a[0]); a[1] = fmaf(c0, bf_hi(u0.x), a[1]);
        a[2] = fmaf(c0, bf_lo(u0.y), a[2]); a[3] = fmaf(c0, bf_hi(u0.y), a[3]);
        a[4] = fmaf(c0, bf_lo(u0.z), a[4]); a[5] = fmaf(c0, bf_hi(u0.z), a[5]);
        a[6] = fmaf(c0, bf_lo(u0.w), a[6]); a[7] = fmaf(c0, bf_hi(u0.w), a[7]);
        a[0] = fmaf(c1, bf_lo(u1.x), a[0]); a[1] = fmaf(c1, bf_hi(u1.x), a[1]);
        a[2] = fmaf(c1, bf_lo(u1.y), a[2]); a[3] = fmaf(c1, bf_hi(u1.y), a[3]);
        a[4] = fmaf(c1, bf_lo(u1.z), a[4]); a[5] = fmaf(c1, bf_hi(u1.z), a[5]);
        a[6] = fmaf(c1, bf_lo(u1.w), a[6]); a[7] = fmaf(c1, bf_hi(u1.w), a[7]);
        a[0] = fmaf(c2, bf_lo(u2.x), a[0]); a[1] = fmaf(c2, bf_hi(u2.x), a[1]);
        a[2] = fmaf(c2, bf_lo(u2.y), a[2]); a[3] = fmaf(c2, bf_hi(u2.y), a[3]);
        a[4] = fmaf(c2, bf_lo(u2.z), a[4]); a[5] = fmaf(c2, bf_hi(u2.z), a[5]);
        a[6] = fmaf(c2, bf_lo(u2.w), a[6]); a[7] = fmaf(c2, bf_hi(u2.w), a[7]);
        a[0] = fmaf(c3, bf_lo(u3.x), a[0]); a[1] = fmaf(c3, bf_hi(u3.x), a[1]);
        a[2] = fmaf(c3, bf_lo(u3.y), a[2]); a[3] = fmaf(c3, bf_hi(u3.y), a[3]);
        a[4] = fmaf(c3, bf_lo(u3.z), a[4]); a[5] = fmaf(c3, bf_hi(u3.z), a[5]);
        a[6] = fmaf(c3, bf_lo(u3.w), a[6]); a[7] = fmaf(c3, bf_hi(u3.w), a[7]);
    }

    float dd = dinv[node];
    float dd2 = dd * dd;
    uint4 u = xb[(size_t)node * 16 + fl];
    float s[8] = { bf_lo(u.x), bf_hi(u.x), bf_lo(u.y), bf_hi(u.y),
                   bf_lo(u.z), bf_hi(u.z), bf_lo(u.w), bf_hi(u.w) };
    uint4 p;
    float o0 = fmaf(dd, a[0], dd2 * s[0]), o1 = fmaf(dd, a[1], dd2 * s[1]);
    float o2 = fmaf(dd, a[2], dd2 * s[2]), o3 = fmaf(dd, a[3], dd2 * s[3]);
    float o4 = fmaf(dd, a[4], dd2 * s[4]), o5 = fmaf(dd, a[5], dd2 * s[5]);
    float o6 = fmaf(dd, a[6], dd2 * s[6]), o7 = fmaf(dd, a[7], dd2 * s[7]);
    p.x = (uint)f2bf(o0) | ((uint)f2bf(o1) << 16);
    p.y = (uint)f2bf(o2) | ((uint)f2bf(o3) << 16);
    p.z = (uint)f2bf(o4) | ((uint)f2bf(o5) << 16);
    p.w = (uint)f2bf(o6) | ((uint)f2bf(o7) << 16);
    ((uint4*)outp)[(size_t)node * 16 + fl] = p;
    if (NVEC && fl == 0) nvec[node] = fmaf(dd, sc, dd2);
}

// ---------- final MFMA GEMM: out[16r][128] fp32 = G2[16r][128]bf16 @ W12t[128][128]
//            + nvec[r]*bvec[c] + b2[c] ----------
__global__ void __launch_bounds__(256)
k_gemm_out(const ushort* __restrict__ A, const ushort* __restrict__ Wt,
           const float* __restrict__ nvec, const float* __restrict__ bvec,
           const float* __restrict__ b2, float* __restrict__ out) {
    constexpr int K = 128, NC = 128, KC = 4, TPW = 2;
    const int lane = threadIdx.x & 63;
    const int wave = threadIdx.x >> 6;
    const int row0 = blockIdx.x * 16;
    const int r = row0 + (lane & 15);
    const int ksub = (lane >> 4) * 8;

    f32x4 acc[TPW];
    int col[TPW];
    #pragma unroll
    for (int t = 0; t < TPW; ++t) {
        acc[t] = (f32x4){0.f, 0.f, 0.f, 0.f};
        col[t] = (wave * TPW + t) * 16 + (lane & 15);
    }
    #pragma unroll
    for (int kc = 0; kc < KC; ++kc) {
        bf16x8 af = *(const bf16x8*)(A + (size_t)r * K + kc * 32 + ksub);
        #pragma unroll
        for (int t = 0; t < TPW; ++t) {
            bf16x8 bf = *(const bf16x8*)(Wt + (size_t)col[t] * K + kc * 32 + ksub);
            acc[t] = __builtin_amdgcn_mfma_f32_16x16x32_bf16(af, bf, acc[t], 0, 0, 0);
        }
    }
    const int rb = row0 + (lane >> 4) * 4;
    float nv[4];
    #pragma unroll
    for (int e = 0; e < 4; ++e) nv[e] = nvec[rb + e];
    #pragma unroll
    for (int t = 0; t < TPW; ++t) {
        float bv = bvec[col[t]];
        float bb = b2[col[t]];
        #pragma unroll
        for (int e = 0; e < 4; ++e) {
            out[(size_t)(rb + e) * NC + col[t]] = acc[t][e] + nv[e] * bv + bb;
        }
    }
}

extern "C" void kernel_launch(void* const* d_in, const int* in_sizes, int n_in,
                              void* d_out, int out_size, void* d_ws, size_t ws_size,
                              hipStream_t stream) {
    const float* emb = (const float*)d_in[0];   // [50000][128]
    const float* W1  = (const float*)d_in[1];   // [128][256]
    const float* b1  = (const float*)d_in[2];   // [256]
    const float* W2  = (const float*)d_in[3];   // [256][128]
    const float* b2  = (const float*)d_in[4];   // [128]
    const int*   ei  = (const int*)d_in[5];     // [2][800000]
    const int* src = ei;
    const int* dst = ei + N_EDGES;

    char* ws = (char*)d_ws;
    float*  dinv    = (float*) (ws);                    // 200 KB
    int*    counts  = (int*)   (ws + (256ull << 10));   // 200 KB
    int*    row_ptr = (int*)   (ws + (512ull << 10));   // 200 KB + 4
    int*    bsum    = (int*)   (ws + (768ull << 10));   // 784 B
    ushort* rank    = (ushort*)(ws + (1ull << 20));     // 1.6 MB  (1..2.6)
    uint*   csr     = (uint*)  (ws + (3ull << 20));     // 3.2 MB  (3..6.2)
    ushort* W12t    = (ushort*)(ws + (6656ull << 10));  // 32 KB   (6.5MB)
    float*  bvec    = (float*) (ws + (6720ull << 10));  // 512 B
    float*  nvec    = (float*) (ws + (6784ull << 10));  // 200 KB
    uint*   emb_h   = (uint*)  (ws + (7ull  << 20));    // 12.8 MB (7..19.8)
    uint*   G       = (uint*)  (ws + (20ull << 20));    // 12.8 MB (20..32.8)
    uint*   G2      = (uint*)  (ws + (33ull << 20));    // 12.8 MB (33..45.8)
    float*  out     = (float*)d_out;

    // fused prep: emb->bf16, zero counts, W12t/bvec
    k_prep<<<3386, 256, 0, stream>>>(emb, W1, W2, b1, emb_h, W12t, bvec, counts);

    // CSR build + normalization (scanb folded into scatter_rp)
    k_histrank<<<(N_EDGES + 255) / 256, 256, 0, stream>>>(dst, counts, rank);
    k_blocksum<<<NB, 256, 0, stream>>>(counts, bsum);
    k_scatter_rp<<<NB, 256, 0, stream>>>(counts, bsum, row_ptr, dinv);
    k_fillr<<<(N_EDGES + 255) / 256, 256, 0, stream>>>(src, dst, rank, row_ptr, dinv, csr);

    // out = (N^2 emb) @ (W1W2) + (N·1)(b1W2) + b2
    k_gatherq<false><<<3125, 256, 0, stream>>>(emb_h, csr, row_ptr, dinv, G, nullptr);
    k_gatherq<true><<<3125, 256, 0, stream>>>(G, csr, row_ptr, dinv, G2, nvec);
    k_gemm_out<<<N_NODES / 16, 256, 0, stream>>>((const ushort*)G2, W12t, nvec, bvec, b2, out);
}